// Round 5
// baseline (827.496 us; speedup 1.0000x reference)
//
#include <hip/hip_runtime.h>
#include <math.h>

// Model dims
#define D_MODEL 256
#define NTOK    8192      // B*S
#define SEQ     512
#define NB      16
#define NH      8
#define DHEAD   32
#define NE      8
#define EHID    1024
#define CSTRIDE 32        // counts[] cacheline stride (ints)

typedef __attribute__((ext_vector_type(8))) short short8;
typedef __attribute__((ext_vector_type(4))) float floatx4;
typedef unsigned short ushort_t;

__device__ __forceinline__ ushort_t bf16r(float f) {
    unsigned int u = __float_as_uint(f);
    u += 0x7fffu + ((u >> 16) & 1u);     // round-to-nearest-even
    return (ushort_t)(u >> 16);
}
__device__ __forceinline__ float bf2f(ushort_t b) {
    return __uint_as_float(((unsigned)b) << 16);
}

// ---------------------------------------------------------------------------
// Fused fp32 -> bf16 conversion of ALL weights (both layers), one launch.
// Region layout in wball (bf16 elems):
//   [0)        in_proj  2*196608 = 393216
//   [393216)   out_proj 2*65536  = 131072
//   [524288)   w1       2*2097152= 4194304
//   [4718592)  w2       2*2097152= 4194304   total 8912896
// ---------------------------------------------------------------------------
__global__ __launch_bounds__(256) void wconv_all(
    const float* __restrict__ in_proj_w, const float* __restrict__ out_proj_w,
    const float* __restrict__ w1, const float* __restrict__ w2,
    ushort_t* __restrict__ wball)
{
    const int g = blockIdx.x * 256 + threadIdx.x;   // quad index
    const float* src; ushort_t* dst; int lo;
    if (g < 98304)        { src = in_proj_w;  dst = wball;           lo = g; }
    else if (g < 131072)  { src = out_proj_w; dst = wball + 393216;  lo = g - 98304; }
    else if (g < 1179648) { src = w1;         dst = wball + 524288;  lo = g - 131072; }
    else                  { src = w2;         dst = wball + 4718592; lo = g - 1179648; }
    float4 v = *(const float4*)(src + (size_t)lo * 4);
    ushort_t o[4] = { bf16r(v.x), bf16r(v.y), bf16r(v.z), bf16r(v.w) };
    *(uint2*)(dst + (size_t)lo * 4) = *(uint2*)o;
}

// ---------------------------------------------------------------------------
// Embedding + positional encoding + pad mask. Writes h (fp32) and hb (bf16).
// ---------------------------------------------------------------------------
__global__ __launch_bounds__(256) void embed_kernel(
    const int* __restrict__ x, const float* __restrict__ emb,
    float* __restrict__ h, ushort_t* __restrict__ hb, int* __restrict__ pad)
{
    __shared__ float wred[4];
    const int n = blockIdx.x;
    const int d = threadIdx.x;
    const int wave = d >> 6;
    const int s = n & (SEQ - 1);
    const int tok = x[n];
    float v = emb[tok * D_MODEL + d] * 16.0f;   // sqrt(256)
    const int j = d >> 1;
    const float c = -9.210340371976184f / 256.0f;
    const float div = expf((float)(2 * j) * c);
    const float ang = (float)s * div;
    v += (d & 1) ? cosf(ang) : sinf(ang);
    h[n * D_MODEL + d] = v;
    hb[n * D_MODEL + d] = bf16r(v);
    float sm = v;
    for (int o = 1; o < 64; o <<= 1) sm += __shfl_xor(sm, o);
    if ((d & 63) == 0) wred[wave] = sm;
    __syncthreads();
    if (d == 0) pad[n] = ((wred[0] + wred[1] + wred[2] + wred[3]) == 0.0f) ? 1 : 0;
}

// ---------------------------------------------------------------------------
// Templated bf16 MFMA GEMM: C[M,N] = A[M,K] @ B[N,K]^T + bias[N]
// BM x BN tile, BK=64, 256 threads (4 waves in 2x2 -> wave tile BM/2 x BN/2).
// Segmented (MoE) mode when counts != nullptr (padded stride CSTRIDE).
// ---------------------------------------------------------------------------
#define GF_RELU    1
#define GF_OUTBF16 2
#define GF_GATHER  4
#define GF_SCATTER 8

template<int BM, int BN>
__global__ __launch_bounds__(256) void gemm_t(
    const ushort_t* __restrict__ A, const ushort_t* __restrict__ Bw,
    const float* __restrict__ bias, void* __restrict__ Cout,
    int M, int N, int K,
    const int* __restrict__ counts,
    const int* __restrict__ perm, const float* __restrict__ topw,
    int flags)
{
    constexpr int MI = BM / 32;   // A staging row-groups
    constexpr int NI = BN / 32;   // B staging row-groups
    constexpr int MF = BM / 32;   // wave M-frags (wave tile BM/2 = MF*16)
    constexpr int NF = BN / 32;   // wave N-frags
    __shared__ ushort_t As[BM][72];
    __shared__ ushort_t Bs[BN][72];
    const int e = blockIdx.z;
    int cnt, off = 0;
    if (counts) {
        cnt = counts[e * CSTRIDE];
        if ((int)blockIdx.y * BM >= cnt) return;
        for (int i = 0; i < e; i++) off += counts[i * CSTRIDE];
    } else { cnt = M; }
    const ushort_t* Bp = Bw + (size_t)e * N * K;
    const float* bp = bias + (size_t)e * N;
    const int m0 = blockIdx.y * BM, n0 = blockIdx.x * BN;
    const int tid = threadIdx.x;
    const int srow = tid >> 3;          // 0..31
    const int kc = (tid & 7) * 8;       // 0..56
    // A row bases (gather-aware), fixed across K iterations
    size_t arow[MI];
#pragma unroll
    for (int i = 0; i < MI; i++) {
        const int r = m0 + i * 32 + srow;
        const bool v = r < cnt;
        if (flags & GF_GATHER) arow[i] = (size_t)perm[off + (v ? r : 0)];
        else                   arow[i] = (size_t)(off + (v ? r : 0));
    }
    const int lane = tid & 63, wave = tid >> 6;
    const int wm = (wave & 1) * (BM / 2), wn = (wave >> 1) * (BN / 2);
    const int fr = lane & 15, fk = (lane >> 4) * 8;
    floatx4 acc[MF][NF];
#pragma unroll
    for (int i = 0; i < MF; i++)
#pragma unroll
        for (int jj = 0; jj < NF; jj++) acc[i][jj] = (floatx4){0.f, 0.f, 0.f, 0.f};

    for (int k0 = 0; k0 < K; k0 += 64) {
        uint4 av[MI], bv[NI];
#pragma unroll
        for (int i = 0; i < MI; i++)
            av[i] = *(const uint4*)(A + arow[i] * K + k0 + kc);
#pragma unroll
        for (int i = 0; i < NI; i++)
            bv[i] = *(const uint4*)(Bp + (size_t)(n0 + i * 32 + srow) * K + k0 + kc);
        __syncthreads();
#pragma unroll
        for (int i = 0; i < MI; i++) *(uint4*)&As[i * 32 + srow][kc] = av[i];
#pragma unroll
        for (int i = 0; i < NI; i++) *(uint4*)&Bs[i * 32 + srow][kc] = bv[i];
        __syncthreads();
#pragma unroll
        for (int ks = 0; ks < 2; ks++) {
            const int ko = ks * 32 + fk;
            short8 fa[MF], fb[NF];
#pragma unroll
            for (int m = 0; m < MF; m++) fa[m] = *(const short8*)&As[wm + m * 16 + fr][ko];
#pragma unroll
            for (int n = 0; n < NF; n++) fb[n] = *(const short8*)&Bs[wn + n * 16 + fr][ko];
#pragma unroll
            for (int m = 0; m < MF; m++)
#pragma unroll
                for (int n = 0; n < NF; n++)
                    acc[m][n] = __builtin_amdgcn_mfma_f32_16x16x32_bf16(fa[m], fb[n], acc[m][n], 0, 0, 0);
        }
    }
    const int crow0 = (lane >> 4) * 4;
    const int ccol = lane & 15;
#pragma unroll
    for (int m = 0; m < MF; m++) {
#pragma unroll
        for (int n = 0; n < NF; n++) {
            const int gcol = n0 + wn + n * 16 + ccol;
            const float bsv = bp[gcol];
#pragma unroll
            for (int r = 0; r < 4; r++) {
                const int grow = m0 + wm + m * 16 + crow0 + r;
                if (grow >= cnt) continue;
                float v = acc[m][n][r] + bsv;
                if (flags & GF_RELU) v = fmaxf(v, 0.f);
                if (flags & GF_SCATTER) {
                    const int tok = perm[off + grow];
                    ((float*)Cout)[(size_t)tok * N + gcol] = v * topw[tok];
                } else if (flags & GF_OUTBF16) {
                    ((ushort_t*)Cout)[(size_t)(off + grow) * N + gcol] = bf16r(v);
                } else {
                    ((float*)Cout)[(size_t)(off + grow) * N + gcol] = v;
                }
            }
        }
    }
}

// ---------------------------------------------------------------------------
// MFMA flash-style attention (verified round 3).
// ---------------------------------------------------------------------------
__global__ __launch_bounds__(256) void attn_kernel(
    const ushort_t* __restrict__ qkvb, const int* __restrict__ pad,
    ushort_t* __restrict__ ctxb)
{
    __shared__ ushort_t Kt[64 * 40];
    __shared__ ushort_t Vt[32 * 72];
    __shared__ ushort_t Ps[64 * 72];
    __shared__ float padf[512];
    const int tid = threadIdx.x;
    const int lane = tid & 63;
    const int wave = tid >> 6;
    const int quad = lane >> 4;
    const int l16  = lane & 15;
    const int bid = blockIdx.x;
    const int qt = bid & 7;
    const int hh = (bid >> 3) & 7;
    const int b = bid >> 6;
    const int q0 = wave * 16;

    padf[tid]       = (float)pad[b * SEQ + tid];
    padf[tid + 256] = (float)pad[b * SEQ + 256 + tid];

    short8 qfrag = *(const short8*)(qkvb +
        (size_t)(b * SEQ + qt * 64 + q0 + l16) * 768 + hh * 32 + quad * 8);

    const int skey = tid >> 2;
    const int schunk = (tid & 3) * 8;

    floatx4 o0 = {0.f,0.f,0.f,0.f}, o1 = {0.f,0.f,0.f,0.f};
    float lsum[4] = {0.f, 0.f, 0.f, 0.f};
    const float scale = 0.17677669529663687f;

    for (int t = 0; t < 8; t++) {
        const int kbase = b * SEQ + t * 64;
        __syncthreads();
        uint4 kv = *(const uint4*)(qkvb + (size_t)(kbase + skey) * 768 + 256 + hh * 32 + schunk);
        *(uint4*)&Kt[skey * 40 + schunk] = kv;
        uint4 vv = *(const uint4*)(qkvb + (size_t)(kbase + skey) * 768 + 512 + hh * 32 + schunk);
        ushort_t vs[8]; *(uint4*)vs = vv;
#pragma unroll
        for (int j = 0; j < 8; j++) {
            const int d = schunk + j;
            Vt[d * 72 + (skey ^ ((d >> 3) << 3))] = vs[j];
        }
        __syncthreads();
        floatx4 sfr[4];
#pragma unroll
        for (int fn = 0; fn < 4; fn++) {
            short8 kf = *(const short8*)&Kt[(fn * 16 + l16) * 40 + quad * 8];
            sfr[fn] = __builtin_amdgcn_mfma_f32_16x16x32_bf16(
                qfrag, kf, (floatx4){0.f,0.f,0.f,0.f}, 0, 0, 0);
        }
#pragma unroll
        for (int fn = 0; fn < 4; fn++) {
            const int keyl = fn * 16 + l16;
            const float pv = padf[t * 64 + keyl];
#pragma unroll
            for (int r = 0; r < 4; r++) {
                float p = (pv != 0.f) ? 0.f : __expf(sfr[fn][r] * scale);
                ushort_t pb = bf16r(p);
                lsum[r] += bf2f(pb);
                Ps[(q0 + quad * 4 + r) * 72 + keyl] = pb;
            }
        }
#pragma unroll
        for (int kc = 0; kc < 2; kc++) {
            short8 pf = *(const short8*)&Ps[(q0 + l16) * 72 + kc * 32 + quad * 8];
            {
                const int d = l16;
                short8 vf = *(const short8*)&Vt[d * 72 + ((kc * 32 + quad * 8) ^ ((d >> 3) << 3))];
                o0 = __builtin_amdgcn_mfma_f32_16x16x32_bf16(pf, vf, o0, 0, 0, 0);
            }
            {
                const int d = 16 + l16;
                short8 vf = *(const short8*)&Vt[d * 72 + ((kc * 32 + quad * 8) ^ ((d >> 3) << 3))];
                o1 = __builtin_amdgcn_mfma_f32_16x16x32_bf16(pf, vf, o1, 0, 0, 0);
            }
        }
    }
#pragma unroll
    for (int r = 0; r < 4; r++) {
        float v = lsum[r];
        v += __shfl_xor(v, 1); v += __shfl_xor(v, 2);
        v += __shfl_xor(v, 4); v += __shfl_xor(v, 8);
        lsum[r] = 1.f / v;
    }
    const int nq = b * SEQ + qt * 64 + q0 + quad * 4;
#pragma unroll
    for (int r = 0; r < 4; r++) {
        ushort_t* outp = ctxb + (size_t)(nq + r) * 256 + hh * 32;
        outp[l16]      = bf16r(o0[r] * lsum[r]);
        outp[16 + l16] = bf16r(o1[r] * lsum[r]);
    }
}

// ---------------------------------------------------------------------------
// Residual add + LayerNorm (in place into h, plus bf16 copy hb).
// ---------------------------------------------------------------------------
__global__ __launch_bounds__(256) void add_ln(
    float* __restrict__ h, const float* __restrict__ add,
    const float* __restrict__ g, const float* __restrict__ b,
    ushort_t* __restrict__ hb)
{
    __shared__ float wred[8];
    const int n = blockIdx.x;
    const int d = threadIdx.x;
    const int wave = d >> 6;
    const float v = h[n * D_MODEL + d] + add[n * D_MODEL + d];
    float s = v;
    for (int o = 1; o < 64; o <<= 1) s += __shfl_xor(s, o);
    if ((d & 63) == 0) wred[wave] = s;
    __syncthreads();
    const float mu = (wred[0] + wred[1] + wred[2] + wred[3]) * (1.0f / 256.0f);
    const float c = v - mu;
    float cs = c * c;
    for (int o = 1; o < 64; o <<= 1) cs += __shfl_xor(cs, o);
    if ((d & 63) == 0) wred[4 + wave] = cs;
    __syncthreads();
    const float var = (wred[4] + wred[5] + wred[6] + wred[7]) * (1.0f / 256.0f);
    const float o = c * rsqrtf(var + 1e-5f) * g[d] + b[d];
    h[n * D_MODEL + d] = o;
    hb[n * D_MODEL + d] = bf16r(o);
}

// ---------------------------------------------------------------------------
// Gate v2 (verified round 4): 128 tokens/block, LDS histogram, 8 padded
// global atomics per block.
// ---------------------------------------------------------------------------
__global__ __launch_bounds__(256) void gate_kernel(
    const float* __restrict__ h, const float* __restrict__ gw,
    const float* __restrict__ gb, int* __restrict__ top_idx,
    float* __restrict__ top_w, int* __restrict__ pos, int* __restrict__ counts)
{
    __shared__ int lidx[128];
    __shared__ int lpos[128];
    __shared__ int hist[NE];
    __shared__ int base[NE];
    const int wave = threadIdx.x >> 6;
    const int lane = threadIdx.x & 63;
    const int t0 = blockIdx.x * 128 + wave * 32;
    float4 gwr[NE];
#pragma unroll
    for (int e = 0; e < NE; e++)
        gwr[e] = *(const float4*)&gw[e * D_MODEL + lane * 4];
    float gbr[NE];
#pragma unroll
    for (int e = 0; e < NE; e++) gbr[e] = gb[e];

    for (int i = 0; i < 32; i++) {
        const int n = t0 + i;
        float4 hv = *(const float4*)&h[(size_t)n * D_MODEL + lane * 4];
        float lg[NE];
#pragma unroll
        for (int e = 0; e < NE; e++)
            lg[e] = hv.x * gwr[e].x + hv.y * gwr[e].y + hv.z * gwr[e].z + hv.w * gwr[e].w;
#pragma unroll
        for (int e = 0; e < NE; e++) {
            float v = lg[e];
            for (int o = 1; o < 64; o <<= 1) v += __shfl_xor(v, o);
            lg[e] = v;
        }
        if (lane == 0) {
            float best = -1e30f; int bi = 0;
#pragma unroll
            for (int e = 0; e < NE; e++) {
                lg[e] += gbr[e];
                if (lg[e] > best) { best = lg[e]; bi = e; }
            }
            float ssum = 0.0f;
#pragma unroll
            for (int e = 0; e < NE; e++) ssum += __expf(lg[e] - best);
            top_idx[n] = bi;
            top_w[n] = 1.0f / ssum;
            lidx[wave * 32 + i] = bi;
        }
    }
    __syncthreads();
    if (threadIdx.x < NE) hist[threadIdx.x] = 0;
    __syncthreads();
    if (threadIdx.x < 128)
        lpos[threadIdx.x] = atomicAdd(&hist[lidx[threadIdx.x]], 1);
    __syncthreads();
    if (threadIdx.x < NE)
        base[threadIdx.x] = atomicAdd(&counts[threadIdx.x * CSTRIDE], hist[threadIdx.x]);
    __syncthreads();
    if (threadIdx.x < 128)
        pos[blockIdx.x * 128 + threadIdx.x] = base[lidx[threadIdx.x]] + lpos[threadIdx.x];
}

__global__ __launch_bounds__(256) void scatter_perm(
    const int* __restrict__ top_idx, const int* __restrict__ pos,
    const int* __restrict__ counts, int* __restrict__ perm)
{
    __shared__ int offs_s[NE];
    if (threadIdx.x < NE) {
        int a = 0;
        for (int i = 0; i < (int)threadIdx.x; i++) a += counts[i * CSTRIDE];
        offs_s[threadIdx.x] = a;
    }
    __syncthreads();
    const int n = blockIdx.x * 256 + threadIdx.x;
    if (n < NTOK) perm[offs_s[top_idx[n]] + pos[n]] = n;
}

// ---------------------------------------------------------------------------
// Masked mean pool, stage 1: 16x16 blocks, partial sums via atomics.
// ---------------------------------------------------------------------------
__global__ __launch_bounds__(256) void pool1(
    const float* __restrict__ h, const int* __restrict__ pad,
    float* __restrict__ pooled, float* __restrict__ cntb)
{
    const int b = blockIdx.x, c = blockIdx.y, d = threadIdx.x;
    float s = 0.0f; int cnt = 0;
    for (int i = 0; i < 32; i++) {
        const int idx = b * SEQ + c * 32 + i;
        if (!pad[idx]) { s += h[(size_t)idx * D_MODEL + d]; cnt++; }
    }
    atomicAdd(&pooled[b * D_MODEL + d], s);
    if (d == 0) atomicAdd(&cntb[b], (float)cnt);
}

__global__ __launch_bounds__(128) void cls_kernel(
    const float* __restrict__ pooled, const float* __restrict__ cntb,
    const float* __restrict__ fc1w, const float* __restrict__ fc1b,
    const float* __restrict__ fc2w, const float* __restrict__ fc2b,
    float* __restrict__ out)
{
    __shared__ float zs[128];
    const int b = blockIdx.x;
    const int j = threadIdx.x;
    const float invc = 1.0f / fmaxf(cntb[b], 1.0f);
    float s = 0.0f;
    for (int d = 0; d < D_MODEL; d++) s += pooled[b * D_MODEL + d] * fc1w[j * D_MODEL + d];
    zs[j] = fmaxf(s * invc + fc1b[j], 0.0f);
    __syncthreads();
    if (j < 2) {
        float o = fc2b[j];
        for (int i = 0; i < 128; i++) o += zs[i] * fc2w[j * 128 + i];
        out[b * 2 + j] = o;
    }
}

// ---------------------------------------------------------------------------
extern "C" void kernel_launch(void* const* d_in, const int* in_sizes, int n_in,
                              void* d_out, int out_size, void* d_ws, size_t ws_size,
                              hipStream_t stream)
{
    const int*   x          = (const int*)d_in[0];
    const float* emb        = (const float*)d_in[1];
    const float* in_proj_w  = (const float*)d_in[2];
    const float* in_proj_b  = (const float*)d_in[3];
    const float* out_proj_w = (const float*)d_in[4];
    const float* out_proj_b = (const float*)d_in[5];
    const float* ln1_g      = (const float*)d_in[6];
    const float* ln1_b      = (const float*)d_in[7];
    const float* ln2_g      = (const float*)d_in[8];
    const float* ln2_b      = (const float*)d_in[9];
    const float* gate_w     = (const float*)d_in[10];
    const float* gate_b     = (const float*)d_in[11];
    const float* w1         = (const float*)d_in[12];
    const float* b1         = (const float*)d_in[13];
    const float* w2         = (const float*)d_in[14];
    const float* b2         = (const float*)d_in[15];
    const float* fc1_w      = (const float*)d_in[16];
    const float* fc1_b      = (const float*)d_in[17];
    const float* fc2_w      = (const float*)d_in[18];
    const float* fc2_b      = (const float*)d_in[19];
    float* out = (float*)d_out;

    // workspace layout (float slots)
    float* ws = (float*)d_ws;
    float*    h      = ws;                          // 2,097,152 f
    float*    tmp    = ws + 2097152;                // 2,097,152 f
    ushort_t* qkvb   = (ushort_t*)(ws + 4194304);   // 8192*768 bf16
    ushort_t* ctxb   = (ushort_t*)(ws + 7340032);   // 8192*256 bf16
    ushort_t* ehb    = (ushort_t*)(ws + 4194304);   // 8192*1024 bf16 aliases qkvb+ctxb
    ushort_t* hb     = (ushort_t*)(ws + 8388608);   // 8192*256 bf16
    float*    top_w  = ws + 10485760;               // 8192
    float*    pooled = ws + 10493952;               // 4096
    float*    cntb   = ws + 10498048;               // 16
    int* ipart   = (int*)(ws + 10498064);
    int* pad     = ipart;              // 8192
    int* top_idx = ipart + 8192;
    int* pos     = ipart + 16384;
    int* perm    = ipart + 24576;
    int* counts  = ipart + 32768;      // NE*CSTRIDE
    ushort_t* wball = (ushort_t*)(ws + 10531088);   // 8,912,896 bf16 (17.8 MB)

    // all-weight bf16 conversion, one launch (2228224 quads / 256)
    wconv_all<<<8704, 256, 0, stream>>>(in_proj_w, out_proj_w, w1, w2, wball);
    embed_kernel<<<NTOK, 256, 0, stream>>>(x, emb, h, hb, pad);
    hipMemsetAsync(pooled, 0, (NB * D_MODEL + NB) * sizeof(float), stream);

    for (int l = 0; l < 2; l++) {
        const ushort_t* inb_l  = wball + (size_t)l * 196608;
        const ushort_t* outb_l = wball + 393216 + (size_t)l * 65536;
        const ushort_t* w1b_l  = wball + 524288 + (size_t)l * 2097152;
        const ushort_t* w2b_l  = wball + 4718592 + (size_t)l * 2097152;

        // --- qkv projection: [8192,256] x [768,256]^T -> qkvb (bf16) ---
        gemm_t<128, 128><<<dim3(768 / 128, NTOK / 128, 1), 256, 0, stream>>>(
            hb, inb_l, in_proj_b + l * 768, qkvb, NTOK, 768, 256,
            nullptr, nullptr, nullptr, GF_OUTBF16);
        // --- attention (MFMA flash) -> ctxb ---
        attn_kernel<<<NB * NH * (SEQ / 64), 256, 0, stream>>>(qkvb, pad, ctxb);
        // --- output projection -> tmp (fp32) ---
        gemm_t<128, 64><<<dim3(256 / 64, NTOK / 128, 1), 256, 0, stream>>>(
            ctxb, outb_l, out_proj_b + l * 256, tmp, NTOK, 256, 256,
            nullptr, nullptr, nullptr, 0);
        add_ln<<<NTOK, 256, 0, stream>>>(h, tmp, ln1_g + l * 256, ln1_b + l * 256, hb);
        // --- MoE routing ---
        hipMemsetAsync(counts, 0, NE * CSTRIDE * sizeof(int), stream);
        gate_kernel<<<NTOK / 128, 256, 0, stream>>>(
            h, gate_w + l * NE * 256, gate_b + l * NE, top_idx, top_w, pos, counts);
        scatter_perm<<<NTOK / 256, 256, 0, stream>>>(top_idx, pos, counts, perm);
        // --- MoE expert GEMMs (routed expert only) ---
        gemm_t<128, 128><<<dim3(EHID / 128, NTOK / 128, NE), 256, 0, stream>>>(
            hb, w1b_l, b1 + l * NE * EHID, ehb, 0, EHID, 256,
            counts, perm, nullptr, GF_GATHER | GF_RELU | GF_OUTBF16);
        gemm_t<128, 64><<<dim3(D_MODEL / 64, NTOK / 128, NE), 256, 0, stream>>>(
            ehb, w2b_l, b2 + l * NE * 256, tmp, 0, D_MODEL, 1024,
            counts, perm, top_w, GF_SCATTER);
        add_ln<<<NTOK, 256, 0, stream>>>(h, tmp, ln2_g + l * 256, ln2_b + l * 256, hb);
    }

    pool1<<<dim3(NB, 16), 256, 0, stream>>>(h, pad, pooled, cntb);
    cls_kernel<<<NB, 128, 0, stream>>>(pooled, cntb, fc1_w, fc1_b, fc2_w, fc2_b, out);
}

// Round 6
// 462.288 us; speedup vs baseline: 1.7900x; 1.7900x over previous
//
#include <hip/hip_runtime.h>
#include <math.h>

// Model dims
#define D_MODEL 256
#define NTOK    8192      // B*S
#define SEQ     512
#define NB      16
#define NH      8
#define DHEAD   32
#define NE      8
#define EHID    1024
#define CSTRIDE 32        // counts[] cacheline stride (ints)

typedef __attribute__((ext_vector_type(8))) short short8;
typedef __attribute__((ext_vector_type(4))) float floatx4;
typedef unsigned short ushort_t;

__device__ __forceinline__ ushort_t bf16r(float f) {
    unsigned int u = __float_as_uint(f);
    u += 0x7fffu + ((u >> 16) & 1u);     // round-to-nearest-even
    return (ushort_t)(u >> 16);
}
__device__ __forceinline__ float bf2f(ushort_t b) {
    return __uint_as_float(((unsigned)b) << 16);
}

// ---------------------------------------------------------------------------
// Fused fp32 -> bf16 conversion of ALL weights (both layers), one launch.
// Region layout in wball (bf16 elems):
//   [0)        in_proj  2*196608 = 393216
//   [393216)   out_proj 2*65536  = 131072
//   [524288)   w1       2*2097152= 4194304
//   [4718592)  w2       2*2097152= 4194304   total 8912896
// ---------------------------------------------------------------------------
__global__ __launch_bounds__(256) void wconv_all(
    const float* __restrict__ in_proj_w, const float* __restrict__ out_proj_w,
    const float* __restrict__ w1, const float* __restrict__ w2,
    ushort_t* __restrict__ wball)
{
    const int g = blockIdx.x * 256 + threadIdx.x;   // quad index
    const float* src; ushort_t* dst; int lo;
    if (g < 98304)        { src = in_proj_w;  dst = wball;           lo = g; }
    else if (g < 131072)  { src = out_proj_w; dst = wball + 393216;  lo = g - 98304; }
    else if (g < 1179648) { src = w1;         dst = wball + 524288;  lo = g - 131072; }
    else                  { src = w2;         dst = wball + 4718592; lo = g - 1179648; }
    float4 v = *(const float4*)(src + (size_t)lo * 4);
    ushort_t o[4] = { bf16r(v.x), bf16r(v.y), bf16r(v.z), bf16r(v.w) };
    *(uint2*)(dst + (size_t)lo * 4) = *(uint2*)o;
}

// ---------------------------------------------------------------------------
// Embedding + positional encoding + pad mask. Writes h (fp32) and hb (bf16).
// ---------------------------------------------------------------------------
__global__ __launch_bounds__(256) void embed_kernel(
    const int* __restrict__ x, const float* __restrict__ emb,
    float* __restrict__ h, ushort_t* __restrict__ hb, int* __restrict__ pad)
{
    __shared__ float wred[4];
    const int n = blockIdx.x;
    const int d = threadIdx.x;
    const int wave = d >> 6;
    const int s = n & (SEQ - 1);
    const int tok = x[n];
    float v = emb[tok * D_MODEL + d] * 16.0f;   // sqrt(256)
    const int j = d >> 1;
    const float c = -9.210340371976184f / 256.0f;
    const float div = expf((float)(2 * j) * c);
    const float ang = (float)s * div;
    v += (d & 1) ? cosf(ang) : sinf(ang);
    h[n * D_MODEL + d] = v;
    hb[n * D_MODEL + d] = bf16r(v);
    float sm = v;
    for (int o = 1; o < 64; o <<= 1) sm += __shfl_xor(sm, o);
    if ((d & 63) == 0) wred[wave] = sm;
    __syncthreads();
    if (d == 0) pad[n] = ((wred[0] + wred[1] + wred[2] + wred[3]) == 0.0f) ? 1 : 0;
}

// ---------------------------------------------------------------------------
// bf16 MFMA GEMM (round-4 verified config): C[M,N] = A[M,K] @ B[N,K]^T + bias
// 64x64 tile, BK=64, 256 threads (4 waves, 2x2), mfma_f32_16x16x32_bf16.
// VGPR 48, no scratch (verified). Segmented (MoE) mode when counts != nullptr.
// ---------------------------------------------------------------------------
#define GF_RELU    1
#define GF_OUTBF16 2
#define GF_GATHER  4
#define GF_SCATTER 8

__global__ __launch_bounds__(256) void mfma_gemm(
    const ushort_t* __restrict__ A, const ushort_t* __restrict__ Bw,
    const float* __restrict__ bias, void* __restrict__ Cout,
    int M, int N, int K,
    const int* __restrict__ counts,
    const int* __restrict__ perm, const float* __restrict__ topw,
    int flags)
{
    __shared__ ushort_t As[64][72];   // 64 rows x (64 + 8 pad) bf16
    __shared__ ushort_t Bs[64][72];
    const int e = blockIdx.z;
    int cnt, off = 0;
    if (counts) {
        cnt = counts[e * CSTRIDE];
        if ((int)blockIdx.y * 64 >= cnt) return;
        for (int i = 0; i < e; i++) off += counts[i * CSTRIDE];
    } else { cnt = M; }
    const ushort_t* Bp = Bw + (size_t)e * N * K;
    const float* bp = bias + (size_t)e * N;
    const int m0 = blockIdx.y * 64, n0 = blockIdx.x * 64;
    const int tid = threadIdx.x;
    const int sr0 = tid >> 3;          // 0..31
    const int kc0 = (tid & 7) * 8;     // 0..56
    const int r0 = m0 + sr0, r1 = r0 + 32;
    const bool v0 = r0 < cnt, v1 = r1 < cnt;
    size_t a0, a1;
    if (flags & GF_GATHER) {
        a0 = (size_t)perm[off + (v0 ? r0 : 0)];
        a1 = (size_t)perm[off + (v1 ? r1 : 0)];
    } else {
        a0 = (size_t)(off + (v0 ? r0 : 0));
        a1 = (size_t)(off + (v1 ? r1 : 0));
    }
    const ushort_t* Ap0 = A + a0 * K + kc0;
    const ushort_t* Ap1 = A + a1 * K + kc0;
    const ushort_t* Bp0 = Bp + (size_t)(n0 + sr0) * K + kc0;
    const ushort_t* Bp1 = Bp + (size_t)(n0 + sr0 + 32) * K + kc0;
    const int lane = tid & 63, wave = tid >> 6;
    const int wm = (wave & 1) * 32, wn = (wave >> 1) * 32;
    const int fr = lane & 15, fk = (lane >> 4) * 8;
    floatx4 acc[2][2];
#pragma unroll
    for (int i = 0; i < 2; i++)
#pragma unroll
        for (int jj = 0; jj < 2; jj++) acc[i][jj] = (floatx4){0.f, 0.f, 0.f, 0.f};

    for (int k0 = 0; k0 < K; k0 += 64) {
        uint4 av0 = *(const uint4*)(Ap0 + k0);
        uint4 av1 = *(const uint4*)(Ap1 + k0);
        uint4 bv0 = *(const uint4*)(Bp0 + k0);
        uint4 bv1 = *(const uint4*)(Bp1 + k0);
        __syncthreads();
        *(uint4*)&As[sr0][kc0]      = av0;
        *(uint4*)&As[sr0 + 32][kc0] = av1;
        *(uint4*)&Bs[sr0][kc0]      = bv0;
        *(uint4*)&Bs[sr0 + 32][kc0] = bv1;
        __syncthreads();
#pragma unroll
        for (int ks = 0; ks < 2; ks++) {
            const int ko = ks * 32 + fk;
            short8 fa0 = *(const short8*)&As[wm + fr][ko];
            short8 fa1 = *(const short8*)&As[wm + 16 + fr][ko];
            short8 fb0 = *(const short8*)&Bs[wn + fr][ko];
            short8 fb1 = *(const short8*)&Bs[wn + 16 + fr][ko];
            acc[0][0] = __builtin_amdgcn_mfma_f32_16x16x32_bf16(fa0, fb0, acc[0][0], 0, 0, 0);
            acc[0][1] = __builtin_amdgcn_mfma_f32_16x16x32_bf16(fa0, fb1, acc[0][1], 0, 0, 0);
            acc[1][0] = __builtin_amdgcn_mfma_f32_16x16x32_bf16(fa1, fb0, acc[1][0], 0, 0, 0);
            acc[1][1] = __builtin_amdgcn_mfma_f32_16x16x32_bf16(fa1, fb1, acc[1][1], 0, 0, 0);
        }
    }
    const int crow0 = (lane >> 4) * 4;
    const int ccol = lane & 15;
#pragma unroll
    for (int fm = 0; fm < 2; fm++) {
#pragma unroll
        for (int fn = 0; fn < 2; fn++) {
            const int gcol = n0 + wn + fn * 16 + ccol;
            const float bsv = bp[gcol];
#pragma unroll
            for (int r = 0; r < 4; r++) {
                const int grow = m0 + wm + fm * 16 + crow0 + r;
                if (grow >= cnt) continue;
                float v = acc[fm][fn][r] + bsv;
                if (flags & GF_RELU) v = fmaxf(v, 0.f);
                if (flags & GF_SCATTER) {
                    const int tok = perm[off + grow];
                    ((float*)Cout)[(size_t)tok * N + gcol] = v * topw[tok];
                } else if (flags & GF_OUTBF16) {
                    ((ushort_t*)Cout)[(size_t)(off + grow) * N + gcol] = bf16r(v);
                } else {
                    ((float*)Cout)[(size_t)(off + grow) * N + gcol] = v;
                }
            }
        }
    }
}

// ---------------------------------------------------------------------------
// MFMA flash-style attention (verified round 3).
// ---------------------------------------------------------------------------
__global__ __launch_bounds__(256) void attn_kernel(
    const ushort_t* __restrict__ qkvb, const int* __restrict__ pad,
    ushort_t* __restrict__ ctxb)
{
    __shared__ ushort_t Kt[64 * 40];
    __shared__ ushort_t Vt[32 * 72];
    __shared__ ushort_t Ps[64 * 72];
    __shared__ float padf[512];
    const int tid = threadIdx.x;
    const int lane = tid & 63;
    const int wave = tid >> 6;
    const int quad = lane >> 4;
    const int l16  = lane & 15;
    const int bid = blockIdx.x;
    const int qt = bid & 7;
    const int hh = (bid >> 3) & 7;
    const int b = bid >> 6;
    const int q0 = wave * 16;

    padf[tid]       = (float)pad[b * SEQ + tid];
    padf[tid + 256] = (float)pad[b * SEQ + 256 + tid];

    short8 qfrag = *(const short8*)(qkvb +
        (size_t)(b * SEQ + qt * 64 + q0 + l16) * 768 + hh * 32 + quad * 8);

    const int skey = tid >> 2;
    const int schunk = (tid & 3) * 8;

    floatx4 o0 = {0.f,0.f,0.f,0.f}, o1 = {0.f,0.f,0.f,0.f};
    float lsum[4] = {0.f, 0.f, 0.f, 0.f};
    const float scale = 0.17677669529663687f;

    for (int t = 0; t < 8; t++) {
        const int kbase = b * SEQ + t * 64;
        __syncthreads();
        uint4 kv = *(const uint4*)(qkvb + (size_t)(kbase + skey) * 768 + 256 + hh * 32 + schunk);
        *(uint4*)&Kt[skey * 40 + schunk] = kv;
        uint4 vv = *(const uint4*)(qkvb + (size_t)(kbase + skey) * 768 + 512 + hh * 32 + schunk);
        ushort_t vs[8]; *(uint4*)vs = vv;
#pragma unroll
        for (int j = 0; j < 8; j++) {
            const int d = schunk + j;
            Vt[d * 72 + (skey ^ ((d >> 3) << 3))] = vs[j];
        }
        __syncthreads();
        floatx4 sfr[4];
#pragma unroll
        for (int fn = 0; fn < 4; fn++) {
            short8 kf = *(const short8*)&Kt[(fn * 16 + l16) * 40 + quad * 8];
            sfr[fn] = __builtin_amdgcn_mfma_f32_16x16x32_bf16(
                qfrag, kf, (floatx4){0.f,0.f,0.f,0.f}, 0, 0, 0);
        }
#pragma unroll
        for (int fn = 0; fn < 4; fn++) {
            const int keyl = fn * 16 + l16;
            const float pv = padf[t * 64 + keyl];
#pragma unroll
            for (int r = 0; r < 4; r++) {
                float p = (pv != 0.f) ? 0.f : __expf(sfr[fn][r] * scale);
                ushort_t pb = bf16r(p);
                lsum[r] += bf2f(pb);
                Ps[(q0 + quad * 4 + r) * 72 + keyl] = pb;
            }
        }
#pragma unroll
        for (int kc = 0; kc < 2; kc++) {
            short8 pf = *(const short8*)&Ps[(q0 + l16) * 72 + kc * 32 + quad * 8];
            {
                const int d = l16;
                short8 vf = *(const short8*)&Vt[d * 72 + ((kc * 32 + quad * 8) ^ ((d >> 3) << 3))];
                o0 = __builtin_amdgcn_mfma_f32_16x16x32_bf16(pf, vf, o0, 0, 0, 0);
            }
            {
                const int d = 16 + l16;
                short8 vf = *(const short8*)&Vt[d * 72 + ((kc * 32 + quad * 8) ^ ((d >> 3) << 3))];
                o1 = __builtin_amdgcn_mfma_f32_16x16x32_bf16(pf, vf, o1, 0, 0, 0);
            }
        }
    }
#pragma unroll
    for (int r = 0; r < 4; r++) {
        float v = lsum[r];
        v += __shfl_xor(v, 1); v += __shfl_xor(v, 2);
        v += __shfl_xor(v, 4); v += __shfl_xor(v, 8);
        lsum[r] = 1.f / v;
    }
    const int nq = b * SEQ + qt * 64 + q0 + quad * 4;
#pragma unroll
    for (int r = 0; r < 4; r++) {
        ushort_t* outp = ctxb + (size_t)(nq + r) * 256 + hh * 32;
        outp[l16]      = bf16r(o0[r] * lsum[r]);
        outp[16 + l16] = bf16r(o1[r] * lsum[r]);
    }
}

// ---------------------------------------------------------------------------
// Residual add + LayerNorm (in place into h, plus bf16 copy hb).
// ---------------------------------------------------------------------------
__global__ __launch_bounds__(256) void add_ln(
    float* __restrict__ h, const float* __restrict__ add,
    const float* __restrict__ g, const float* __restrict__ b,
    ushort_t* __restrict__ hb)
{
    __shared__ float wred[8];
    const int n = blockIdx.x;
    const int d = threadIdx.x;
    const int wave = d >> 6;
    const float v = h[n * D_MODEL + d] + add[n * D_MODEL + d];
    float s = v;
    for (int o = 1; o < 64; o <<= 1) s += __shfl_xor(s, o);
    if ((d & 63) == 0) wred[wave] = s;
    __syncthreads();
    const float mu = (wred[0] + wred[1] + wred[2] + wred[3]) * (1.0f / 256.0f);
    const float c = v - mu;
    float cs = c * c;
    for (int o = 1; o < 64; o <<= 1) cs += __shfl_xor(cs, o);
    if ((d & 63) == 0) wred[4 + wave] = cs;
    __syncthreads();
    const float var = (wred[4] + wred[5] + wred[6] + wred[7]) * (1.0f / 256.0f);
    const float o = c * rsqrtf(var + 1e-5f) * g[d] + b[d];
    h[n * D_MODEL + d] = o;
    hb[n * D_MODEL + d] = bf16r(o);
}

// ---------------------------------------------------------------------------
// Gate v2 (verified round 4): 128 tokens/block, LDS histogram, 8 padded
// global atomics per block.
// ---------------------------------------------------------------------------
__global__ __launch_bounds__(256) void gate_kernel(
    const float* __restrict__ h, const float* __restrict__ gw,
    const float* __restrict__ gb, int* __restrict__ top_idx,
    float* __restrict__ top_w, int* __restrict__ pos, int* __restrict__ counts)
{
    __shared__ int lidx[128];
    __shared__ int lpos[128];
    __shared__ int hist[NE];
    __shared__ int base[NE];
    const int wave = threadIdx.x >> 6;
    const int lane = threadIdx.x & 63;
    const int t0 = blockIdx.x * 128 + wave * 32;
    float4 gwr[NE];
#pragma unroll
    for (int e = 0; e < NE; e++)
        gwr[e] = *(const float4*)&gw[e * D_MODEL + lane * 4];
    float gbr[NE];
#pragma unroll
    for (int e = 0; e < NE; e++) gbr[e] = gb[e];

    for (int i = 0; i < 32; i++) {
        const int n = t0 + i;
        float4 hv = *(const float4*)&h[(size_t)n * D_MODEL + lane * 4];
        float lg[NE];
#pragma unroll
        for (int e = 0; e < NE; e++)
            lg[e] = hv.x * gwr[e].x + hv.y * gwr[e].y + hv.z * gwr[e].z + hv.w * gwr[e].w;
#pragma unroll
        for (int e = 0; e < NE; e++) {
            float v = lg[e];
            for (int o = 1; o < 64; o <<= 1) v += __shfl_xor(v, o);
            lg[e] = v;
        }
        if (lane == 0) {
            float best = -1e30f; int bi = 0;
#pragma unroll
            for (int e = 0; e < NE; e++) {
                lg[e] += gbr[e];
                if (lg[e] > best) { best = lg[e]; bi = e; }
            }
            float ssum = 0.0f;
#pragma unroll
            for (int e = 0; e < NE; e++) ssum += __expf(lg[e] - best);
            top_idx[n] = bi;
            top_w[n] = 1.0f / ssum;
            lidx[wave * 32 + i] = bi;
        }
    }
    __syncthreads();
    if (threadIdx.x < NE) hist[threadIdx.x] = 0;
    __syncthreads();
    if (threadIdx.x < 128)
        lpos[threadIdx.x] = atomicAdd(&hist[lidx[threadIdx.x]], 1);
    __syncthreads();
    if (threadIdx.x < NE)
        base[threadIdx.x] = atomicAdd(&counts[threadIdx.x * CSTRIDE], hist[threadIdx.x]);
    __syncthreads();
    if (threadIdx.x < 128)
        pos[blockIdx.x * 128 + threadIdx.x] = base[lidx[threadIdx.x]] + lpos[threadIdx.x];
}

__global__ __launch_bounds__(256) void scatter_perm(
    const int* __restrict__ top_idx, const int* __restrict__ pos,
    const int* __restrict__ counts, int* __restrict__ perm)
{
    __shared__ int offs_s[NE];
    if (threadIdx.x < NE) {
        int a = 0;
        for (int i = 0; i < (int)threadIdx.x; i++) a += counts[i * CSTRIDE];
        offs_s[threadIdx.x] = a;
    }
    __syncthreads();
    const int n = blockIdx.x * 256 + threadIdx.x;
    if (n < NTOK) perm[offs_s[top_idx[n]] + pos[n]] = n;
}

// ---------------------------------------------------------------------------
// Masked mean pool, stage 1: 16x16 blocks, partial sums via atomics.
// ---------------------------------------------------------------------------
__global__ __launch_bounds__(256) void pool1(
    const float* __restrict__ h, const int* __restrict__ pad,
    float* __restrict__ pooled, float* __restrict__ cntb)
{
    const int b = blockIdx.x, c = blockIdx.y, d = threadIdx.x;
    float s = 0.0f; int cnt = 0;
    for (int i = 0; i < 32; i++) {
        const int idx = b * SEQ + c * 32 + i;
        if (!pad[idx]) { s += h[(size_t)idx * D_MODEL + d]; cnt++; }
    }
    atomicAdd(&pooled[b * D_MODEL + d], s);
    if (d == 0) atomicAdd(&cntb[b], (float)cnt);
}

__global__ __launch_bounds__(128) void cls_kernel(
    const float* __restrict__ pooled, const float* __restrict__ cntb,
    const float* __restrict__ fc1w, const float* __restrict__ fc1b,
    const float* __restrict__ fc2w, const float* __restrict__ fc2b,
    float* __restrict__ out)
{
    __shared__ float zs[128];
    const int b = blockIdx.x;
    const int j = threadIdx.x;
    const float invc = 1.0f / fmaxf(cntb[b], 1.0f);
    float s = 0.0f;
    for (int d = 0; d < D_MODEL; d++) s += pooled[b * D_MODEL + d] * fc1w[j * D_MODEL + d];
    zs[j] = fmaxf(s * invc + fc1b[j], 0.0f);
    __syncthreads();
    if (j < 2) {
        float o = fc2b[j];
        for (int i = 0; i < 128; i++) o += zs[i] * fc2w[j * 128 + i];
        out[b * 2 + j] = o;
    }
}

// ---------------------------------------------------------------------------
extern "C" void kernel_launch(void* const* d_in, const int* in_sizes, int n_in,
                              void* d_out, int out_size, void* d_ws, size_t ws_size,
                              hipStream_t stream)
{
    const int*   x          = (const int*)d_in[0];
    const float* emb        = (const float*)d_in[1];
    const float* in_proj_w  = (const float*)d_in[2];
    const float* in_proj_b  = (const float*)d_in[3];
    const float* out_proj_w = (const float*)d_in[4];
    const float* out_proj_b = (const float*)d_in[5];
    const float* ln1_g      = (const float*)d_in[6];
    const float* ln1_b      = (const float*)d_in[7];
    const float* ln2_g      = (const float*)d_in[8];
    const float* ln2_b      = (const float*)d_in[9];
    const float* gate_w     = (const float*)d_in[10];
    const float* gate_b     = (const float*)d_in[11];
    const float* w1         = (const float*)d_in[12];
    const float* b1         = (const float*)d_in[13];
    const float* w2         = (const float*)d_in[14];
    const float* b2         = (const float*)d_in[15];
    const float* fc1_w      = (const float*)d_in[16];
    const float* fc1_b      = (const float*)d_in[17];
    const float* fc2_w      = (const float*)d_in[18];
    const float* fc2_b      = (const float*)d_in[19];
    float* out = (float*)d_out;

    // workspace layout (float slots)
    float* ws = (float*)d_ws;
    float*    h      = ws;                          // 2,097,152 f
    float*    tmp    = ws + 2097152;                // 2,097,152 f
    ushort_t* qkvb   = (ushort_t*)(ws + 4194304);   // 8192*768 bf16
    ushort_t* ctxb   = (ushort_t*)(ws + 7340032);   // 8192*256 bf16
    ushort_t* ehb    = (ushort_t*)(ws + 4194304);   // 8192*1024 bf16 aliases qkvb+ctxb
    ushort_t* hb     = (ushort_t*)(ws + 8388608);   // 8192*256 bf16
    float*    top_w  = ws + 10485760;               // 8192
    float*    pooled = ws + 10493952;               // 4096
    float*    cntb   = ws + 10498048;               // 16
    int* ipart   = (int*)(ws + 10498064);
    int* pad     = ipart;              // 8192
    int* top_idx = ipart + 8192;
    int* pos     = ipart + 16384;
    int* perm    = ipart + 24576;
    int* counts  = ipart + 32768;      // NE*CSTRIDE
    ushort_t* wball = (ushort_t*)(ws + 10531088);   // 8,912,896 bf16 (17.8 MB)

    // all-weight bf16 conversion, one launch (2228224 quads / 256)
    wconv_all<<<8704, 256, 0, stream>>>(in_proj_w, out_proj_w, w1, w2, wball);
    embed_kernel<<<NTOK, 256, 0, stream>>>(x, emb, h, hb, pad);
    hipMemsetAsync(pooled, 0, (NB * D_MODEL + NB) * sizeof(float), stream);

    for (int l = 0; l < 2; l++) {
        const ushort_t* inb_l  = wball + (size_t)l * 196608;
        const ushort_t* outb_l = wball + 393216 + (size_t)l * 65536;
        const ushort_t* w1b_l  = wball + 524288 + (size_t)l * 2097152;
        const ushort_t* w2b_l  = wball + 4718592 + (size_t)l * 2097152;

        // --- qkv projection: [8192,256] x [768,256]^T -> qkvb (bf16) ---
        mfma_gemm<<<dim3(768 / 64, NTOK / 64, 1), 256, 0, stream>>>(
            hb, inb_l, in_proj_b + l * 768, qkvb, NTOK, 768, 256,
            nullptr, nullptr, nullptr, GF_OUTBF16);
        // --- attention (MFMA flash) -> ctxb ---
        attn_kernel<<<NB * NH * (SEQ / 64), 256, 0, stream>>>(qkvb, pad, ctxb);
        // --- output projection -> tmp (fp32) ---
        mfma_gemm<<<dim3(256 / 64, NTOK / 64, 1), 256, 0, stream>>>(
            ctxb, outb_l, out_proj_b + l * 256, tmp, NTOK, 256, 256,
            nullptr, nullptr, nullptr, 0);
        add_ln<<<NTOK, 256, 0, stream>>>(h, tmp, ln1_g + l * 256, ln1_b + l * 256, hb);
        // --- MoE routing ---
        hipMemsetAsync(counts, 0, NE * CSTRIDE * sizeof(int), stream);
        gate_kernel<<<NTOK / 128, 256, 0, stream>>>(
            h, gate_w + l * NE * 256, gate_b + l * NE, top_idx, top_w, pos, counts);
        scatter_perm<<<NTOK / 256, 256, 0, stream>>>(top_idx, pos, counts, perm);
        // --- MoE expert GEMMs (routed expert only) ---
        mfma_gemm<<<dim3(EHID / 64, NTOK / 64, NE), 256, 0, stream>>>(
            hb, w1b_l, b1 + l * NE * EHID, ehb, 0, EHID, 256,
            counts, perm, nullptr, GF_GATHER | GF_RELU | GF_OUTBF16);
        mfma_gemm<<<dim3(D_MODEL / 64, NTOK / 64, NE), 256, 0, stream>>>(
            ehb, w2b_l, b2 + l * NE * 256, tmp, 0, D_MODEL, 1024,
            counts, perm, top_w, GF_SCATTER);
        add_ln<<<NTOK, 256, 0, stream>>>(h, tmp, ln2_g + l * 256, ln2_b + l * 256, hb);
    }

    pool1<<<dim3(NB, 16), 256, 0, stream>>>(h, pad, pooled, cntb);
    cls_kernel<<<NB, 128, 0, stream>>>(pooled, cntb, fc1_w, fc1_b, fc2_w, fc2_b, out);
}